// Round 2
// baseline (213.820 us; speedup 1.0000x reference)
//
#include <hip/hip_runtime.h>
#include <hip/hip_bf16.h>

// QFD loss: out = 0.1 * sum_b diff_b^T A diff_b, A_ij = 1 - |i-j|/85.
// Identity: q = S^2 - (2/85) * (S*sumL - sumL2), where
//   S = sum_i d_i, L_k = prefix sum (k<84), sumL = sum L_k, sumL2 = sum L_k^2.
// O(D) per row -> purely memory-bound (178 MB read; ~20-28 us floor w/ L3).
//
// R1: 64 rows/block (21.76 KB LDS) -> 7 blocks/CU resident (28/32 waves)
// vs R0's 2 blocks @ 44 KB. Latency-bound fix: more in-flight loads,
// cross-block phase overlap. __launch_bounds__(256,7) caps VGPR at <=73.

#define QFD_D 85
#define ROWS_PER_BLOCK 64
#define THREADS 256

__global__ __launch_bounds__(THREADS, 7) void qfd_kernel(
    const float* __restrict__ in, const float* __restrict__ tgt,
    float* __restrict__ out) {
    // 64 rows * 85 floats * 4 B = 21,760 B of LDS
    __shared__ float diff[ROWS_PER_BLOCK * QFD_D];
    __shared__ float wsum[THREADS / 64];

    const int tid = threadIdx.x;
    const int E = ROWS_PER_BLOCK * QFD_D;      // 5440 floats per block
    const int base = blockIdx.x * E;           // max ~22.3M -> fits int32

    // ---- Stage |in - tgt| into LDS, coalesced float4 (base%4==0) ----
    const float4* in4 = reinterpret_cast<const float4*>(in + base);
    const float4* tg4 = reinterpret_cast<const float4*>(tgt + base);
    float4* df4 = reinterpret_cast<float4*>(diff);
    for (int idx = tid; idx < E / 4; idx += THREADS) {  // 1360 float4s
        float4 a = in4[idx];
        float4 b = tg4[idx];
        float4 r;
        r.x = fabsf(a.x - b.x);
        r.y = fabsf(a.y - b.y);
        r.z = fabsf(a.z - b.z);
        r.w = fabsf(a.w - b.w);
        df4[idx] = r;
    }
    __syncthreads();

    // ---- Per-row sequential scan (threads 0..63; LDS bank stride
    // 85 mod 32 = 21, coprime with 32 -> only 2-way aliasing = free) ----
    float q = 0.0f;
    if (tid < ROWS_PER_BLOCK) {
        const float* d = &diff[tid * QFD_D];
        float L = 0.0f, sumL = 0.0f, sumL2 = 0.0f;
        #pragma unroll 4
        for (int k = 0; k < QFD_D - 1; ++k) {
            L += d[k];
            sumL += L;
            sumL2 = fmaf(L, L, sumL2);
        }
        const float S = L + d[QFD_D - 1];
        q = fmaf(S, S, -(2.0f / 85.0f) * (S * sumL - sumL2));
    }

    // ---- Block reduction: wave shuffle -> LDS -> one atomicAdd/block ----
    #pragma unroll
    for (int off = 32; off > 0; off >>= 1)
        q += __shfl_down(q, off, 64);
    if ((tid & 63) == 0) wsum[tid >> 6] = q;
    __syncthreads();
    if (tid == 0) {
        float s = 0.0f;
        #pragma unroll
        for (int w = 0; w < THREADS / 64; ++w) s += wsum[w];
        atomicAdd(out, 0.1f * s);
    }
}

extern "C" void kernel_launch(void* const* d_in, const int* in_sizes, int n_in,
                              void* d_out, int out_size, void* d_ws, size_t ws_size,
                              hipStream_t stream) {
    const float* in  = (const float*)d_in[0];
    const float* tgt = (const float*)d_in[1];
    float* out = (float*)d_out;

    const int B = in_sizes[0] / QFD_D;         // 262144
    const int grid = B / ROWS_PER_BLOCK;       // 4096 blocks

    // d_out is re-poisoned to 0xAA before every timed launch; zero it here
    // (hipMemsetAsync is graph-capturable).
    hipMemsetAsync(d_out, 0, sizeof(float), stream);
    qfd_kernel<<<grid, THREADS, 0, stream>>>(in, tgt, out);
}

// Round 3
// 193.359 us; speedup vs baseline: 1.1058x; 1.1058x over previous
//
#include <hip/hip_runtime.h>
#include <hip/hip_bf16.h>

// QFD loss: out = 0.1 * sum_b diff_b^T A diff_b, A_ij = 1 - |i-j|/85.
// Identity: q = S^2 - (2/85) * (S*sumL - sumL2), where
//   S = sum_i d_i, L_k = prefix sum (k<84), sumL = sum L_k, sumL2 = sum L_k^2.
//
// R2: R1's counters (dur UP with occupancy UP; VALU 4.7%, HBM 12%, all idle)
// fingered the 4096 same-address device-scope atomicAdds (~15-20 ns each
// serialized = ~70 us tail; R0->R1 delta = 7ns x 2048 extra atomics).
// -> two-stage reduction: block partials to d_ws (distinct addresses),
//    tiny second kernel reduces. Also: 5-deep register-batched staging
//    loads for memory-level parallelism (10 loads in flight/thread).

#define QFD_D 85
#define ROWS_PER_BLOCK 64
#define THREADS 256

__global__ __launch_bounds__(THREADS, 7) void qfd_kernel(
    const float* __restrict__ in, const float* __restrict__ tgt,
    float* __restrict__ partial) {
    // 64 rows * 85 floats * 4 B = 21,760 B of LDS
    __shared__ float diff[ROWS_PER_BLOCK * QFD_D];
    __shared__ float wsum[THREADS / 64];

    const int tid = threadIdx.x;
    const int E = ROWS_PER_BLOCK * QFD_D;      // 5440 floats per block
    const int base = blockIdx.x * E;           // max ~22.3M -> fits int32

    // ---- Stage |in - tgt| into LDS. 1360 float4s = 5*256 + 80.
    // Batch 5 float4-pairs into registers first -> 10 loads in flight. ----
    const float4* in4 = reinterpret_cast<const float4*>(in + base);
    const float4* tg4 = reinterpret_cast<const float4*>(tgt + base);
    float4* df4 = reinterpret_cast<float4*>(diff);

    float4 a[5], b[5];
    #pragma unroll
    for (int j = 0; j < 5; ++j) {
        a[j] = in4[tid + j * THREADS];
        b[j] = tg4[tid + j * THREADS];
    }
    float4 at, bt;
    if (tid < 80) {  // tail: float4s 1280..1359
        at = in4[1280 + tid];
        bt = tg4[1280 + tid];
    }
    #pragma unroll
    for (int j = 0; j < 5; ++j) {
        float4 r;
        r.x = fabsf(a[j].x - b[j].x);
        r.y = fabsf(a[j].y - b[j].y);
        r.z = fabsf(a[j].z - b[j].z);
        r.w = fabsf(a[j].w - b[j].w);
        df4[tid + j * THREADS] = r;
    }
    if (tid < 80) {
        float4 r;
        r.x = fabsf(at.x - bt.x);
        r.y = fabsf(at.y - bt.y);
        r.z = fabsf(at.z - bt.z);
        r.w = fabsf(at.w - bt.w);
        df4[1280 + tid] = r;
    }
    __syncthreads();

    // ---- Per-row sequential scan (threads 0..63; LDS bank stride
    // 85 mod 32 = 21, coprime with 32 -> only 2-way aliasing = free) ----
    float q = 0.0f;
    if (tid < ROWS_PER_BLOCK) {
        const float* d = &diff[tid * QFD_D];
        float L = 0.0f, sumL = 0.0f, sumL2 = 0.0f;
        #pragma unroll 4
        for (int k = 0; k < QFD_D - 1; ++k) {
            L += d[k];
            sumL += L;
            sumL2 = fmaf(L, L, sumL2);
        }
        const float S = L + d[QFD_D - 1];
        q = fmaf(S, S, -(2.0f / 85.0f) * (S * sumL - sumL2));
    }

    // ---- Block reduction -> ONE PLAIN STORE per block (no atomics) ----
    #pragma unroll
    for (int off = 32; off > 0; off >>= 1)
        q += __shfl_down(q, off, 64);
    if ((tid & 63) == 0) wsum[tid >> 6] = q;
    __syncthreads();
    if (tid == 0) {
        float s = 0.0f;
        #pragma unroll
        for (int w = 0; w < THREADS / 64; ++w) s += wsum[w];
        partial[blockIdx.x] = s;
    }
}

// Stage 2: reduce n partials (n = 4096), write 0.1 * sum. One block.
__global__ __launch_bounds__(THREADS) void qfd_reduce_kernel(
    const float* __restrict__ partial, float* __restrict__ out, int n) {
    __shared__ float wsum[THREADS / 64];
    const int tid = threadIdx.x;
    float s = 0.0f;
    for (int i = tid; i < n; i += THREADS) s += partial[i];
    #pragma unroll
    for (int off = 32; off > 0; off >>= 1)
        s += __shfl_down(s, off, 64);
    if ((tid & 63) == 0) wsum[tid >> 6] = s;
    __syncthreads();
    if (tid == 0) {
        float t = 0.0f;
        #pragma unroll
        for (int w = 0; w < THREADS / 64; ++w) t += wsum[w];
        out[0] = 0.1f * t;
    }
}

extern "C" void kernel_launch(void* const* d_in, const int* in_sizes, int n_in,
                              void* d_out, int out_size, void* d_ws, size_t ws_size,
                              hipStream_t stream) {
    const float* in  = (const float*)d_in[0];
    const float* tgt = (const float*)d_in[1];
    float* out = (float*)d_out;
    float* partial = (float*)d_ws;             // 4096 floats = 16 KB scratch

    const int B = in_sizes[0] / QFD_D;         // 262144
    const int grid = B / ROWS_PER_BLOCK;       // 4096 blocks

    qfd_kernel<<<grid, THREADS, 0, stream>>>(in, tgt, partial);
    qfd_reduce_kernel<<<1, THREADS, 0, stream>>>(partial, out, grid);
}